// Round 1
// baseline (191.965 us; speedup 1.0000x reference)
//
#include <hip/hip_runtime.h>
#include <math.h>

#define Bn 8
#define NN 200
#define Cc 256
#define RR (Bn*NN)       // 1600 rows total
#define N_EPS 1e-12f
#define LN_EPS 1e-5f
#define SLOPE 0.01f
#define SCALE 5.0f

// ---------------- block reduction helpers (blockDim.x == 256) ----------------
__device__ __forceinline__ float block_reduce_sum(float v, float* sh) {
    __syncthreads();                       // protect sh reuse across calls
    #pragma unroll
    for (int o = 32; o > 0; o >>= 1) v += __shfl_xor(v, o);
    if ((threadIdx.x & 63) == 0) sh[threadIdx.x >> 6] = v;
    __syncthreads();
    return sh[0] + sh[1] + sh[2] + sh[3];
}

__device__ __forceinline__ float block_reduce_max(float v, float* sh) {
    __syncthreads();
    #pragma unroll
    for (int o = 32; o > 0; o >>= 1) v = fmaxf(v, __shfl_xor(v, o));
    if ((threadIdx.x & 63) == 0) sh[threadIdx.x >> 6] = v;
    __syncthreads();
    return fmaxf(fmaxf(sh[0], sh[1]), fmaxf(sh[2], sh[3]));
}

// ---------------- kernels ----------------

// nf = x / max(||x||_2, 1e-12), rowwise over C=256. grid=RR, block=256
__global__ void k_l2norm(const float* __restrict__ x, float* __restrict__ nf) {
    __shared__ float sh[4];
    int r = blockIdx.x, t = threadIdx.x;
    float v = x[r * Cc + t];
    float ss = block_reduce_sum(v * v, sh);
    float nrm = fmaxf(sqrtf(ss), N_EPS);
    nf[r * Cc + t] = v / nrm;
}

// Y[r,d] = sum_c X[r,c] * W[c*256+d]  (+ bias[d] * (rowscale?rowscale[r]:1))
// 4 rows per block. grid=RR/4, block=256
__global__ void k_gemm_nn(const float* __restrict__ X, const float* __restrict__ W,
                          float* __restrict__ Y, const float* __restrict__ bias,
                          const float* __restrict__ rowscale) {
    __shared__ float sx[4][Cc];
    int r0 = blockIdx.x * 4;
    int t = threadIdx.x;
    #pragma unroll
    for (int k = 0; k < 4; k++) sx[k][t] = X[(r0 + k) * Cc + t];
    __syncthreads();
    float a0 = 0.f, a1 = 0.f, a2 = 0.f, a3 = 0.f;
    #pragma unroll 8
    for (int c = 0; c < Cc; c++) {
        float w = W[c * Cc + t];
        a0 = fmaf(sx[0][c], w, a0);
        a1 = fmaf(sx[1][c], w, a1);
        a2 = fmaf(sx[2][c], w, a2);
        a3 = fmaf(sx[3][c], w, a3);
    }
    if (bias) {
        float bv = bias[t];
        if (rowscale) {
            a0 += bv * rowscale[r0 + 0];
            a1 += bv * rowscale[r0 + 1];
            a2 += bv * rowscale[r0 + 2];
            a3 += bv * rowscale[r0 + 3];
        } else {
            a0 += bv; a1 += bv; a2 += bv; a3 += bv;
        }
    }
    Y[(r0 + 0) * Cc + t] = a0;
    Y[(r0 + 1) * Cc + t] = a1;
    Y[(r0 + 2) * Cc + t] = a2;
    Y[(r0 + 3) * Cc + t] = a3;
}

// A[b,i,j] = dot(P[b,i,:], Q[b,j,:]), K=256. 16x16 tile per block.
// grid = Bn*13*13, block=256
__global__ void k_gemm_nt(const float* __restrict__ P, const float* __restrict__ Q,
                          float* __restrict__ A) {
    __shared__ float sp[16][Cc + 1];
    __shared__ float sq[16][Cc + 1];
    int blk = blockIdx.x;
    int b = blk / 169, rem = blk % 169;
    int i0 = (rem / 13) * 16, j0 = (rem % 13) * 16;
    const float* Pb = P + (size_t)b * NN * Cc;
    const float* Qb = Q + (size_t)b * NN * Cc;
    int tid = threadIdx.x;
    #pragma unroll
    for (int k = 0; k < 16; k++) {
        int rr = k, cc2 = tid;
        sp[rr][cc2] = (i0 + rr < NN) ? Pb[(i0 + rr) * Cc + cc2] : 0.f;
        sq[rr][cc2] = (j0 + rr < NN) ? Qb[(j0 + rr) * Cc + cc2] : 0.f;
    }
    __syncthreads();
    int ti = tid >> 4, tj = tid & 15;
    float acc = 0.f;
    #pragma unroll 8
    for (int c = 0; c < Cc; c++) acc = fmaf(sp[ti][c], sq[tj][c], acc);
    int i = i0 + ti, j = j0 + tj;
    if (i < NN && j < NN) A[(size_t)b * NN * NN + (size_t)i * NN + j] = acc;
}

// diff_prop row transform: e=exp(5*(a-max)); e[i]=0; a=e/max(sum,eps); s=sum(a)
// grid=RR, block=256
__global__ void k_rownorm_dp(float* __restrict__ A, float* __restrict__ s) {
    __shared__ float sh[4];
    int bi = blockIdx.x;
    int b = bi / NN, i = bi % NN;
    float* row = A + (size_t)b * NN * NN + (size_t)i * NN;
    int t = threadIdx.x;
    float v = (t < NN) ? row[t] : -INFINITY;
    float m = block_reduce_max(v, sh);
    float e = 0.f;
    if (t < NN && t != i) e = expf(SCALE * (v - m));
    float sum = block_reduce_sum(e, sh);
    float a = e / fmaxf(sum, N_EPS);
    if (t < NN) row[t] = a;
    float s2 = block_reduce_sum(a, sh);
    if (t == 0) s[bi] = s2;
}

// feat_aggr row transform: standard softmax of 5*(a-max). grid=RR, block=256
__global__ void k_rownorm_sm(float* __restrict__ A) {
    __shared__ float sh[4];
    int bi = blockIdx.x;
    int b = bi / NN, i = bi % NN;
    float* row = A + (size_t)b * NN * NN + (size_t)i * NN;
    int t = threadIdx.x;
    float v = (t < NN) ? row[t] : -INFINITY;
    float m = block_reduce_max(v, sh);
    float e = (t < NN) ? expf(SCALE * (v - m)) : 0.f;
    float sum = block_reduce_sum(e, sh);
    if (t < NN) row[t] = e / sum;
}

// out[bi,c] = sum_j A[b,i,j]*Lf[b,j,c];  mode1: out = s[bi]*lf[bi,c] - out
// grid=RR, block=256
__global__ void k_Amul(const float* __restrict__ A, const float* __restrict__ Lf,
                       const float* __restrict__ lf_orig, const float* __restrict__ s,
                       float* __restrict__ out, int mode) {
    __shared__ float sa[NN];
    int bi = blockIdx.x;
    int b = bi / NN, i = bi % NN;
    int t = threadIdx.x;
    if (t < NN) sa[t] = A[(size_t)b * NN * NN + (size_t)i * NN + t];
    __syncthreads();
    const float* base = Lf + (size_t)b * NN * Cc;
    float acc = 0.f;
    #pragma unroll 4
    for (int j = 0; j < NN; j++) acc = fmaf(sa[j], base[j * Cc + t], acc);
    if (mode == 1) acc = s[bi] * lf_orig[(size_t)bi * Cc + t] - acc;
    out[(size_t)bi * Cc + t] = acc;
}

// LayerNorm over C + LeakyReLU. grid=RR, block=256
__global__ void k_ln_leaky(const float* __restrict__ x, const float* __restrict__ g,
                           const float* __restrict__ bb, float* __restrict__ out) {
    __shared__ float sh[4];
    int r = blockIdx.x, t = threadIdx.x;
    float v = x[r * Cc + t];
    float mean = block_reduce_sum(v, sh) * (1.f / 256.f);
    float d = v - mean;
    float var = block_reduce_sum(d * d, sh) * (1.f / 256.f);
    float y = d / sqrtf(var + LN_EPS) * g[t] + bb[t];
    out[r * Cc + t] = (y >= 0.f) ? y : SLOPE * y;
}

// 32x32-tiled transpose of 256x256: WT[c,d]=W[d,c]. grid=64, block=256
__global__ void k_transpose(const float* __restrict__ W, float* __restrict__ WT) {
    __shared__ float tile[32][33];
    int bx = blockIdx.x & 7, by = blockIdx.x >> 3;
    int tx = threadIdx.x & 31, ty = threadIdx.x >> 5;   // ty 0..7
    #pragma unroll
    for (int k = 0; k < 32; k += 8)
        tile[ty + k][tx] = W[(by * 32 + ty + k) * Cc + bx * 32 + tx];
    __syncthreads();
    #pragma unroll
    for (int k = 0; k < 32; k += 8)
        WT[(bx * 32 + ty + k) * Cc + by * 32 + tx] = tile[tx][ty + k];
}

// v[b,c] = sum_j w[j] * nf[b,j,c]. grid=Bn, block=256
__global__ void k_wsum(const float* __restrict__ nf, const float* __restrict__ w,
                       float* __restrict__ v) {
    int b = blockIdx.x, t = threadIdx.x;
    const float* base = nf + (size_t)b * NN * Cc;
    float acc = 0.f;
    #pragma unroll 4
    for (int j = 0; j < NN; j++) acc = fmaf(w[j], base[j * Cc + t], acc);
    v[b * Cc + t] = acc;
}

// att = sigmoid(nf_i . v_b + pos_i . w[200:209] + b); out = x2 * att. grid=RR
__global__ void k_natt(const float* __restrict__ x2, const float* __restrict__ nf,
                       const float* __restrict__ v, const float* __restrict__ pos,
                       const float* __restrict__ w, const float* __restrict__ nb,
                       float* __restrict__ out) {
    __shared__ float sh[4];
    __shared__ float att_sh;
    int bi = blockIdx.x;
    int b = bi / NN;
    int t = threadIdx.x;
    float dotv = block_reduce_sum(nf[(size_t)bi * Cc + t] * v[b * Cc + t], sh);
    if (t == 0) {
        float p = 0.f;
        #pragma unroll
        for (int k = 0; k < 9; k++) p = fmaf(pos[bi * 9 + k], w[NN + k], p);
        float z = dotv + p + nb[0];
        att_sh = 1.f / (1.f + expf(-z));
    }
    __syncthreads();
    out[(size_t)bi * Cc + t] = x2[(size_t)bi * Cc + t] * att_sh;
}

// ---------------- launcher ----------------
extern "C" void kernel_launch(void* const* d_in, const int* in_sizes, int n_in,
                              void* d_out, int out_size, void* d_ws, size_t ws_size,
                              hipStream_t stream) {
    (void)in_sizes; (void)n_in; (void)out_size; (void)ws_size;
    const float* lf       = (const float*)d_in[0];
    // d_in[1] = global_feat (unused by reference)
    const float* pos      = (const float*)d_in[2];
    const float* dp_adj_w = (const float*)d_in[3];
    const float* dp_aff_w = (const float*)d_in[4];
    const float* dp_aff_b = (const float*)d_in[5];
    const float* dp_ln_g  = (const float*)d_in[6];
    const float* dp_ln_b  = (const float*)d_in[7];
    const float* fa_adj_w = (const float*)d_in[8];
    const float* fa_aff_w = (const float*)d_in[9];
    const float* fa_aff_b = (const float*)d_in[10];
    const float* fa_ln_g  = (const float*)d_in[11];
    const float* fa_ln_b  = (const float*)d_in[12];
    const float* na_w     = (const float*)d_in[13];
    const float* na_b     = (const float*)d_in[14];
    float* out = (float*)d_out;
    float* ws  = (float*)d_ws;

    float* nf  = ws;                 // RR*Cc
    float* M   = nf  + RR * Cc;      // RR*Cc
    float* A   = M   + RR * Cc;      // Bn*NN*NN
    float* s   = A   + Bn * NN * NN; // RR
    float* U   = s   + RR;           // RR*Cc
    float* x1  = U   + RR * Cc;      // RR*Cc
    float* x2  = x1  + RR * Cc;      // RR*Cc
    float* WT1 = x2  + RR * Cc;      // Cc*Cc
    float* WT2 = WT1 + Cc * Cc;      // Cc*Cc
    float* vv  = WT2 + Cc * Cc;      // Bn*Cc

    dim3 blk(256);
    const int NT_GRID = Bn * 13 * 13;

    k_transpose<<<64, blk, 0, stream>>>(dp_aff_w, WT1);
    k_transpose<<<64, blk, 0, stream>>>(fa_aff_w, WT2);

    // -------- stage 1: diff_prop (linearity-collapsed) --------
    k_l2norm<<<RR, blk, 0, stream>>>(lf, nf);
    k_gemm_nn<<<RR / 4, blk, 0, stream>>>(nf, dp_adj_w, M, nullptr, nullptr);
    k_gemm_nt<<<NT_GRID, blk, 0, stream>>>(M, nf, A);
    k_rownorm_dp<<<RR, blk, 0, stream>>>(A, s);
    k_Amul<<<RR, blk, 0, stream>>>(A, lf, lf, s, U, 1);            // U = s*lf - A@lf
    k_gemm_nn<<<RR / 4, blk, 0, stream>>>(U, WT1, M, dp_aff_b, s); // agg = U@W^T + s*b
    k_ln_leaky<<<RR, blk, 0, stream>>>(M, dp_ln_g, dp_ln_b, x1);

    // -------- stage 2: feat_aggr --------
    k_l2norm<<<RR, blk, 0, stream>>>(x1, nf);
    k_gemm_nn<<<RR / 4, blk, 0, stream>>>(nf, fa_adj_w, M, nullptr, nullptr);
    k_gemm_nt<<<NT_GRID, blk, 0, stream>>>(M, nf, A);
    k_rownorm_sm<<<RR, blk, 0, stream>>>(A);
    k_gemm_nn<<<RR / 4, blk, 0, stream>>>(x1, WT2, U, fa_aff_b, nullptr); // lf2
    k_Amul<<<RR, blk, 0, stream>>>(A, U, nullptr, nullptr, M, 0);         // A@lf2
    k_ln_leaky<<<RR, blk, 0, stream>>>(M, fa_ln_g, fa_ln_b, x2);

    // -------- stage 3: node_att (rank-1 collapsed) --------
    k_l2norm<<<RR, blk, 0, stream>>>(x2, nf);
    k_wsum<<<Bn, blk, 0, stream>>>(nf, na_w, vv);
    k_natt<<<RR, blk, 0, stream>>>(x2, nf, vv, pos, na_w, na_b, out);
}

// Round 2
// 146.853 us; speedup vs baseline: 1.3072x; 1.3072x over previous
//
#include <hip/hip_runtime.h>
#include <math.h>

#define Bn 8
#define NN 200
#define Cc 256
#define RR (Bn*NN)       // 1600 rows total
#define N_EPS 1e-12f
#define LN_EPS 1e-5f
#define SLOPE 0.01f
#define SCALE 5.0f

// ---------------- reduction helpers (blockDim.x == 256) ----------------
__device__ __forceinline__ float wave_reduce_sum(float v) {
    #pragma unroll
    for (int o = 32; o > 0; o >>= 1) v += __shfl_xor(v, o);
    return v;
}

__device__ __forceinline__ float block_reduce_sum(float v, float* sh) {
    __syncthreads();
    v = wave_reduce_sum(v);
    if ((threadIdx.x & 63) == 0) sh[threadIdx.x >> 6] = v;
    __syncthreads();
    return sh[0] + sh[1] + sh[2] + sh[3];
}

__device__ __forceinline__ float block_reduce_max(float v, float* sh) {
    __syncthreads();
    #pragma unroll
    for (int o = 32; o > 0; o >>= 1) v = fmaxf(v, __shfl_xor(v, o));
    if ((threadIdx.x & 63) == 0) sh[threadIdx.x >> 6] = v;
    __syncthreads();
    return fmaxf(fmaxf(sh[0], sh[1]), fmaxf(sh[2], sh[3]));
}

// ---------------- shared building block: 4-row (l2norm?) + NN-GEMM ----------------
// Y[r,:] = norm?(X[r,:]) @ W  (+ bias).  One block = 4 rows, wave w owns row blk*4+w.
__device__ __forceinline__ void l2g_block(int blk, const float* __restrict__ X,
        const float* __restrict__ W, float* __restrict__ NF, float* __restrict__ Y,
        const float* __restrict__ bias, int do_norm) {
    __shared__ float sx[4][Cc];
    int t = threadIdx.x, lane = t & 63, wv = t >> 6;
    int r = blk * 4 + wv;
    float4 x = ((const float4*)(X + (size_t)r * Cc))[lane];
    if (do_norm) {
        float ss = wave_reduce_sum(x.x*x.x + x.y*x.y + x.z*x.z + x.w*x.w);
        float inv = 1.f / fmaxf(sqrtf(ss), N_EPS);
        x.x *= inv; x.y *= inv; x.z *= inv; x.w *= inv;
        ((float4*)(NF + (size_t)r * Cc))[lane] = x;
    }
    ((float4*)&sx[wv][0])[lane] = x;
    __syncthreads();
    float a0 = 0.f, a1 = 0.f, a2 = 0.f, a3 = 0.f;
    #pragma unroll 8
    for (int c = 0; c < Cc; c++) {
        float w = W[(size_t)c * Cc + t];
        a0 = fmaf(sx[0][c], w, a0);
        a1 = fmaf(sx[1][c], w, a1);
        a2 = fmaf(sx[2][c], w, a2);
        a3 = fmaf(sx[3][c], w, a3);
    }
    if (bias) { float bv = bias[t]; a0 += bv; a1 += bv; a2 += bv; a3 += bv; }
    int r0 = blk * 4;
    Y[(size_t)(r0+0)*Cc + t] = a0;
    Y[(size_t)(r0+1)*Cc + t] = a1;
    Y[(size_t)(r0+2)*Cc + t] = a2;
    Y[(size_t)(r0+3)*Cc + t] = a3;
}

// ---------------- dispatch 1: nf=l2norm(lf), M=nf@dp_adj, WT1, WT2 ----------------
__global__ void k_pre(const float* __restrict__ lf, const float* __restrict__ dp_adj_w,
                      const float* __restrict__ dp_aff_w, const float* __restrict__ fa_aff_w,
                      float* __restrict__ nf, float* __restrict__ M,
                      float* __restrict__ WT1, float* __restrict__ WT2) {
    int bid = blockIdx.x;
    if (bid < RR/4) { l2g_block(bid, lf, dp_adj_w, nf, M, nullptr, 1); return; }
    // transpose blocks
    int tb = bid - RR/4;
    const float* S; float* D;
    if (tb < 64) { S = dp_aff_w; D = WT1; } else { S = fa_aff_w; D = WT2; tb -= 64; }
    __shared__ float tile[32][33];
    int bx = tb & 7, by = tb >> 3;
    int tx = threadIdx.x & 31, ty = threadIdx.x >> 5;  // ty 0..7
    #pragma unroll
    for (int k = 0; k < 32; k += 8)
        tile[ty + k][tx] = S[(size_t)(by*32 + ty + k) * Cc + bx*32 + tx];
    __syncthreads();
    #pragma unroll
    for (int k = 0; k < 32; k += 8)
        D[(size_t)(bx*32 + ty + k) * Cc + by*32 + tx] = tile[tx][ty + k];
}

// ---------------- dispatch 2: diff_prop per-row mega-kernel ----------------
// 2 rows per block. A-row dots -> dp rownorm -> u = s*lf_i - A@lf -> u@WT1 + s*b -> LN+leaky.
__global__ void k_row1(const float* __restrict__ nf, const float* __restrict__ M,
                       const float* __restrict__ lf, const float* __restrict__ WT1,
                       const float* __restrict__ dp_aff_b, const float* __restrict__ g,
                       const float* __restrict__ bb, float* __restrict__ x1) {
    __shared__ float sa0[NN], sa1[NN];
    __shared__ float su0[Cc], su1[Cc];
    __shared__ float sh[4];
    int t = threadIdx.x, lane = t & 63, wv = t >> 6;
    int b = blockIdx.x / (NN/2);
    int i0 = (blockIdx.x % (NN/2)) * 2;
    size_t base = (size_t)b * NN * Cc;
    // phase A: A[i0,:], A[i0+1,:] via wave-per-j dots (coalesced float4 + shuffle reduce)
    const float4* nfb4 = (const float4*)(nf + base);
    float4 mA = ((const float4*)(M + base + (size_t)i0 * Cc))[lane];
    float4 mB = ((const float4*)(M + base + (size_t)(i0+1) * Cc))[lane];
    for (int j = wv; j < NN; j += 4) {
        float4 q = nfb4[j * 64 + lane];
        float pa = mA.x*q.x + mA.y*q.y + mA.z*q.z + mA.w*q.w;
        float pb = mB.x*q.x + mB.y*q.y + mB.z*q.z + mB.w*q.w;
        #pragma unroll
        for (int o = 32; o > 0; o >>= 1) { pa += __shfl_xor(pa, o); pb += __shfl_xor(pb, o); }
        if (lane == 0) { sa0[j] = pa; sa1[j] = pb; }
    }
    __syncthreads();
    // phase B: dp row transform (exp, zero diag, L1 norm, row sum)
    float s0, s1;
    {
        float v = (t < NN) ? sa0[t] : -INFINITY;
        float m = block_reduce_max(v, sh);
        float e = (t < NN && t != i0) ? expf(SCALE * (v - m)) : 0.f;
        float sum = block_reduce_sum(e, sh);
        float a = e / fmaxf(sum, N_EPS);
        if (t < NN) sa0[t] = a;
        s0 = block_reduce_sum(a, sh);
    }
    {
        float v = (t < NN) ? sa1[t] : -INFINITY;
        float m = block_reduce_max(v, sh);
        float e = (t < NN && t != i0 + 1) ? expf(SCALE * (v - m)) : 0.f;
        float sum = block_reduce_sum(e, sh);
        float a = e / fmaxf(sum, N_EPS);
        if (t < NN) sa1[t] = a;
        s1 = block_reduce_sum(a, sh);
    }
    __syncthreads();
    // phase C: u = s*lf_i - sum_j a_j lf_j   (coalesced over t, LDS broadcast a_j)
    const float* lfb = lf + base;
    float acc0 = 0.f, acc1 = 0.f;
    #pragma unroll 8
    for (int j = 0; j < NN; j++) {
        float xv = lfb[(size_t)j * Cc + t];
        acc0 = fmaf(sa0[j], xv, acc0);
        acc1 = fmaf(sa1[j], xv, acc1);
    }
    su0[t] = s0 * lfb[(size_t)i0 * Cc + t] - acc0;
    su1[t] = s1 * lfb[(size_t)(i0+1) * Cc + t] - acc1;
    __syncthreads();
    // phase D: y = u @ WT1 + s*bias
    float bv = dp_aff_b[t];
    float y0 = bv * s0, y1 = bv * s1;
    #pragma unroll 8
    for (int c = 0; c < Cc; c++) {
        float w = WT1[(size_t)c * Cc + t];
        y0 = fmaf(su0[c], w, y0);
        y1 = fmaf(su1[c], w, y1);
    }
    // phase E: LayerNorm + LeakyReLU
    float gg = g[t], bbv = bb[t];
    {
        float mean = block_reduce_sum(y0, sh) * (1.f/256.f);
        float d = y0 - mean;
        float var = block_reduce_sum(d * d, sh) * (1.f/256.f);
        float z = d / sqrtf(var + LN_EPS) * gg + bbv;
        x1[base + (size_t)i0 * Cc + t] = (z >= 0.f) ? z : SLOPE * z;
    }
    {
        float mean = block_reduce_sum(y1, sh) * (1.f/256.f);
        float d = y1 - mean;
        float var = block_reduce_sum(d * d, sh) * (1.f/256.f);
        float z = d / sqrtf(var + LN_EPS) * gg + bbv;
        x1[base + (size_t)(i0+1) * Cc + t] = (z >= 0.f) ? z : SLOPE * z;
    }
}

// ---------------- dispatch 3: nf2/M2 + lf2 (two independent GEMMs, one launch) ----------------
__global__ void k_mid(const float* __restrict__ x1, const float* __restrict__ fa_adj_w,
                      const float* __restrict__ WT2, const float* __restrict__ fa_aff_b,
                      float* __restrict__ nf, float* __restrict__ M, float* __restrict__ lf2) {
    int bid = blockIdx.x;
    if (bid < RR/4) l2g_block(bid, x1, fa_adj_w, nf, M, nullptr, 1);
    else            l2g_block(bid - RR/4, x1, WT2, nullptr, lf2, fa_aff_b, 0);
}

// ---------------- dispatch 4: feat_aggr per-row mega-kernel (+ nf3 epilogue) ----------------
__global__ void k_row2(const float* __restrict__ nf, const float* __restrict__ M,
                       const float* __restrict__ lf2, const float* __restrict__ g,
                       const float* __restrict__ bb, float* __restrict__ x2,
                       float* __restrict__ nf3) {
    __shared__ float sa0[NN], sa1[NN];
    __shared__ float sh[4];
    int t = threadIdx.x, lane = t & 63, wv = t >> 6;
    int b = blockIdx.x / (NN/2);
    int i0 = (blockIdx.x % (NN/2)) * 2;
    size_t base = (size_t)b * NN * Cc;
    const float4* nfb4 = (const float4*)(nf + base);
    float4 mA = ((const float4*)(M + base + (size_t)i0 * Cc))[lane];
    float4 mB = ((const float4*)(M + base + (size_t)(i0+1) * Cc))[lane];
    for (int j = wv; j < NN; j += 4) {
        float4 q = nfb4[j * 64 + lane];
        float pa = mA.x*q.x + mA.y*q.y + mA.z*q.z + mA.w*q.w;
        float pb = mB.x*q.x + mB.y*q.y + mB.z*q.z + mB.w*q.w;
        #pragma unroll
        for (int o = 32; o > 0; o >>= 1) { pa += __shfl_xor(pa, o); pb += __shfl_xor(pb, o); }
        if (lane == 0) { sa0[j] = pa; sa1[j] = pb; }
    }
    __syncthreads();
    // softmax rows
    {
        float v = (t < NN) ? sa0[t] : -INFINITY;
        float m = block_reduce_max(v, sh);
        float e = (t < NN) ? expf(SCALE * (v - m)) : 0.f;
        float sum = block_reduce_sum(e, sh);
        if (t < NN) sa0[t] = e / sum;
    }
    {
        float v = (t < NN) ? sa1[t] : -INFINITY;
        float m = block_reduce_max(v, sh);
        float e = (t < NN) ? expf(SCALE * (v - m)) : 0.f;
        float sum = block_reduce_sum(e, sh);
        if (t < NN) sa1[t] = e / sum;
    }
    __syncthreads();
    // y = A @ lf2
    const float* l2b = lf2 + base;
    float y0 = 0.f, y1 = 0.f;
    #pragma unroll 8
    for (int j = 0; j < NN; j++) {
        float xv = l2b[(size_t)j * Cc + t];
        y0 = fmaf(sa0[j], xv, y0);
        y1 = fmaf(sa1[j], xv, y1);
    }
    // LN + leaky + l2norm epilogue (for node_att)
    float gg = g[t], bbv = bb[t];
    {
        float mean = block_reduce_sum(y0, sh) * (1.f/256.f);
        float d = y0 - mean;
        float var = block_reduce_sum(d * d, sh) * (1.f/256.f);
        float z = d / sqrtf(var + LN_EPS) * gg + bbv;
        z = (z >= 0.f) ? z : SLOPE * z;
        x2[base + (size_t)i0 * Cc + t] = z;
        float ss = block_reduce_sum(z * z, sh);
        nf3[base + (size_t)i0 * Cc + t] = z / fmaxf(sqrtf(ss), N_EPS);
    }
    {
        float mean = block_reduce_sum(y1, sh) * (1.f/256.f);
        float d = y1 - mean;
        float var = block_reduce_sum(d * d, sh) * (1.f/256.f);
        float z = d / sqrtf(var + LN_EPS) * gg + bbv;
        z = (z >= 0.f) ? z : SLOPE * z;
        x2[base + (size_t)(i0+1) * Cc + t] = z;
        float ss = block_reduce_sum(z * z, sh);
        nf3[base + (size_t)(i0+1) * Cc + t] = z / fmaxf(sqrtf(ss), N_EPS);
    }
}

// ---------------- dispatch 5: vv[b,c] = sum_j w[j]*nf3[b,j,c] ----------------
__global__ void k_wsum(const float* __restrict__ nf3, const float* __restrict__ w,
                       float* __restrict__ vv) {
    int b = blockIdx.x, t = threadIdx.x;
    const float* base = nf3 + (size_t)b * NN * Cc;
    float acc = 0.f;
    #pragma unroll 4
    for (int j = 0; j < NN; j++) acc = fmaf(w[j], base[(size_t)j * Cc + t], acc);
    vv[b * Cc + t] = acc;
}

// ---------------- dispatch 6: out = x2 * sigmoid(nf3.vv + pos.w9 + b), 4 rows/block ----------------
__global__ void k_natt(const float* __restrict__ x2, const float* __restrict__ nf3,
                       const float* __restrict__ vv, const float* __restrict__ pos,
                       const float* __restrict__ w, const float* __restrict__ nb,
                       float* __restrict__ out) {
    int t = threadIdx.x, lane = t & 63, wv = t >> 6;
    int b = blockIdx.x / (NN/4);
    int i = (blockIdx.x % (NN/4)) * 4 + wv;
    size_t bi = (size_t)b * NN + i;
    float4 nv = ((const float4*)(nf3 + bi * Cc))[lane];
    float4 vb = ((const float4*)(vv + (size_t)b * Cc))[lane];
    float val = nv.x*vb.x + nv.y*vb.y + nv.z*vb.z + nv.w*vb.w;
    if (lane < 9) val += pos[bi * 9 + lane] * w[NN + lane];
    val = wave_reduce_sum(val);
    float att = 1.f / (1.f + expf(-(val + nb[0])));
    float4 xo = ((const float4*)(x2 + bi * Cc))[lane];
    xo.x *= att; xo.y *= att; xo.z *= att; xo.w *= att;
    ((float4*)(out + bi * Cc))[lane] = xo;
}

// ---------------- launcher ----------------
extern "C" void kernel_launch(void* const* d_in, const int* in_sizes, int n_in,
                              void* d_out, int out_size, void* d_ws, size_t ws_size,
                              hipStream_t stream) {
    (void)in_sizes; (void)n_in; (void)out_size; (void)ws_size;
    const float* lf       = (const float*)d_in[0];
    const float* pos      = (const float*)d_in[2];
    const float* dp_adj_w = (const float*)d_in[3];
    const float* dp_aff_w = (const float*)d_in[4];
    const float* dp_aff_b = (const float*)d_in[5];
    const float* dp_ln_g  = (const float*)d_in[6];
    const float* dp_ln_b  = (const float*)d_in[7];
    const float* fa_adj_w = (const float*)d_in[8];
    const float* fa_aff_w = (const float*)d_in[9];
    const float* fa_aff_b = (const float*)d_in[10];
    const float* fa_ln_g  = (const float*)d_in[11];
    const float* fa_ln_b  = (const float*)d_in[12];
    const float* na_w     = (const float*)d_in[13];
    const float* na_b     = (const float*)d_in[14];
    float* out = (float*)d_out;
    float* ws  = (float*)d_ws;

    float* nf  = ws;                 // RR*Cc   (reused for nf2)
    float* M   = nf  + RR * Cc;      // RR*Cc   (reused for M2)
    float* x1  = M   + RR * Cc;      // RR*Cc
    float* lf2 = x1  + RR * Cc;      // RR*Cc
    float* x2  = lf2 + RR * Cc;      // RR*Cc
    float* nf3 = x2  + RR * Cc;      // RR*Cc
    float* WT1 = nf3 + RR * Cc;      // Cc*Cc
    float* WT2 = WT1 + Cc * Cc;      // Cc*Cc
    float* vv  = WT2 + Cc * Cc;      // Bn*Cc

    dim3 blk(256);
    k_pre <<<RR/4 + 128, blk, 0, stream>>>(lf, dp_adj_w, dp_aff_w, fa_aff_w, nf, M, WT1, WT2);
    k_row1<<<Bn * NN/2,  blk, 0, stream>>>(nf, M, lf, WT1, dp_aff_b, dp_ln_g, dp_ln_b, x1);
    k_mid <<<RR/4 * 2,   blk, 0, stream>>>(x1, fa_adj_w, WT2, fa_aff_b, nf, M, lf2);
    k_row2<<<Bn * NN/2,  blk, 0, stream>>>(nf, M, lf2, fa_ln_g, fa_ln_b, x2, nf3);
    k_wsum<<<Bn,         blk, 0, stream>>>(nf3, na_w, vv);
    k_natt<<<Bn * NN/4,  blk, 0, stream>>>(x2, nf3, vv, pos, na_w, na_b, out);
}

// Round 3
// 104.418 us; speedup vs baseline: 1.8384x; 1.4064x over previous
//
#include <hip/hip_runtime.h>
#include <math.h>

#define Bn 8
#define NN 200
#define Cc 256
#define RR (Bn*NN)       // 1600 rows total
#define JP 200           // j-stride of transposed nf
#define N_EPS 1e-12f
#define LN_EPS 1e-5f
#define SLOPE 0.01f
#define SCALE 5.0f

// ---------------- reduction helpers (blockDim.x == 256) ----------------
__device__ __forceinline__ float wave_reduce_sum(float v) {
    #pragma unroll
    for (int o = 32; o > 0; o >>= 1) v += __shfl_xor(v, o);
    return v;
}

__device__ __forceinline__ float block_reduce_sum(float v, float* sh) {
    __syncthreads();
    v = wave_reduce_sum(v);
    if ((threadIdx.x & 63) == 0) sh[threadIdx.x >> 6] = v;
    __syncthreads();
    return sh[0] + sh[1] + sh[2] + sh[3];
}

__device__ __forceinline__ float block_reduce_max(float v, float* sh) {
    __syncthreads();
    #pragma unroll
    for (int o = 32; o > 0; o >>= 1) v = fmaxf(v, __shfl_xor(v, o));
    if ((threadIdx.x & 63) == 0) sh[threadIdx.x >> 6] = v;
    __syncthreads();
    return fmaxf(fmaxf(sh[0], sh[1]), fmaxf(sh[2], sh[3]));
}

// ---------------- 4-row GEMM blocks ----------------
// l2-normalize 4 rows of X, write them TRANSPOSED into nfT[b][c][j], Y = nf@W.
__device__ __forceinline__ void gemm4_normT(int blk, const float* __restrict__ X,
        const float* __restrict__ W, float* __restrict__ nfT, float* __restrict__ Y) {
    __shared__ float sx[4][Cc];
    int t = threadIdx.x, lane = t & 63, wv = t >> 6;
    int r0 = blk * 4;
    float4 x = ((const float4*)(X + (size_t)(r0 + wv) * Cc))[lane];
    float ss = wave_reduce_sum(x.x*x.x + x.y*x.y + x.z*x.z + x.w*x.w);
    float inv = 1.f / fmaxf(sqrtf(ss), N_EPS);
    x.x *= inv; x.y *= inv; x.z *= inv; x.w *= inv;
    ((float4*)&sx[wv][0])[lane] = x;
    __syncthreads();
    // transposed write: 4 consecutive j's at column c=t (16B store, stride JP*4 B)
    int b = r0 / NN, i0 = r0 % NN;
    float4 col;
    col.x = sx[0][t]; col.y = sx[1][t]; col.z = sx[2][t]; col.w = sx[3][t];
    *((float4*)(nfT + (size_t)b * Cc * JP + (size_t)t * JP + i0)) = col;
    float a0 = 0.f, a1 = 0.f, a2 = 0.f, a3 = 0.f;
    #pragma unroll 8
    for (int c = 0; c < Cc; c++) {
        float w = W[(size_t)c * Cc + t];
        a0 = fmaf(sx[0][c], w, a0);
        a1 = fmaf(sx[1][c], w, a1);
        a2 = fmaf(sx[2][c], w, a2);
        a3 = fmaf(sx[3][c], w, a3);
    }
    Y[(size_t)(r0+0)*Cc + t] = a0;
    Y[(size_t)(r0+1)*Cc + t] = a1;
    Y[(size_t)(r0+2)*Cc + t] = a2;
    Y[(size_t)(r0+3)*Cc + t] = a3;
}

// plain 4-row GEMM: Y = X@W (+bias)
__device__ __forceinline__ void gemm4_plain(int blk, const float* __restrict__ X,
        const float* __restrict__ W, const float* __restrict__ bias, float* __restrict__ Y) {
    __shared__ float sx[4][Cc];
    int t = threadIdx.x, lane = t & 63, wv = t >> 6;
    int r0 = blk * 4;
    float4 x = ((const float4*)(X + (size_t)(r0 + wv) * Cc))[lane];
    ((float4*)&sx[wv][0])[lane] = x;
    __syncthreads();
    float a0 = 0.f, a1 = 0.f, a2 = 0.f, a3 = 0.f;
    #pragma unroll 8
    for (int c = 0; c < Cc; c++) {
        float w = W[(size_t)c * Cc + t];
        a0 = fmaf(sx[0][c], w, a0);
        a1 = fmaf(sx[1][c], w, a1);
        a2 = fmaf(sx[2][c], w, a2);
        a3 = fmaf(sx[3][c], w, a3);
    }
    if (bias) { float bv = bias[t]; a0 += bv; a1 += bv; a2 += bv; a3 += bv; }
    Y[(size_t)(r0+0)*Cc + t] = a0;
    Y[(size_t)(r0+1)*Cc + t] = a1;
    Y[(size_t)(r0+2)*Cc + t] = a2;
    Y[(size_t)(r0+3)*Cc + t] = a3;
}

// ---------------- dispatch 1: nfT + M, WT1, WT2 ----------------
__global__ void k_pre(const float* __restrict__ lf, const float* __restrict__ dp_adj_w,
                      const float* __restrict__ dp_aff_w, const float* __restrict__ fa_aff_w,
                      float* __restrict__ nfT, float* __restrict__ M,
                      float* __restrict__ WT1, float* __restrict__ WT2) {
    int bid = blockIdx.x;
    if (bid < RR/4) { gemm4_normT(bid, lf, dp_adj_w, nfT, M); return; }
    int tb = bid - RR/4;
    const float* S; float* D;
    if (tb < 64) { S = dp_aff_w; D = WT1; } else { S = fa_aff_w; D = WT2; tb -= 64; }
    __shared__ float tile[32][33];
    int bx = tb & 7, by = tb >> 3;
    int tx = threadIdx.x & 31, ty = threadIdx.x >> 5;
    #pragma unroll
    for (int k = 0; k < 32; k += 8)
        tile[ty + k][tx] = S[(size_t)(by*32 + ty + k) * Cc + bx*32 + tx];
    __syncthreads();
    #pragma unroll
    for (int k = 0; k < 32; k += 8)
        D[(size_t)(bx*32 + ty + k) * Cc + by*32 + tx] = tile[tx][ty + k];
}

// ---------------- dispatch 2: P = lf @ WT1 ----------------
__global__ void k_pre2(const float* __restrict__ lf, const float* __restrict__ WT1,
                       float* __restrict__ P) {
    gemm4_plain(blockIdx.x, lf, WT1, nullptr, P);
}

// ---------------- dispatch 3: diff_prop row kernel (2 rows/block) ----------------
// A-dots (thread-per-j, nfT) -> dp rownorm -> y = s*(P_i+b) - A@P -> LN+leaky
__global__ void k_row1(const float* __restrict__ nfT, const float* __restrict__ M,
                       const float* __restrict__ P, const float* __restrict__ bias,
                       const float* __restrict__ g, const float* __restrict__ bb,
                       float* __restrict__ x1) {
    __shared__ float sm0[Cc], sm1[Cc];
    __shared__ float sa0[NN], sa1[NN];
    __shared__ float sh[4];
    int t = threadIdx.x;
    int b = blockIdx.x / (NN/2);
    int i0 = (blockIdx.x % (NN/2)) * 2;
    size_t base = (size_t)b * NN * Cc;
    sm0[t] = M[base + (size_t)i0 * Cc + t];
    sm1[t] = M[base + (size_t)(i0+1) * Cc + t];
    __syncthreads();
    // phase A: A[i0,j], A[i0+1,j] for j=t (serial c-reduction, coalesced nfT loads)
    if (t < NN) {
        const float* nfc = nfT + (size_t)b * Cc * JP + t;
        float a0 = 0.f, a1 = 0.f;
        #pragma unroll 8
        for (int c = 0; c < Cc; c++) {
            float q = nfc[(size_t)c * JP];
            a0 = fmaf(sm0[c], q, a0);
            a1 = fmaf(sm1[c], q, a1);
        }
        sa0[t] = a0; sa1[t] = a1;
    }
    __syncthreads();
    // phase B: exp(5*(a-max)), zero diag, L1 norm, row-sum s
    float s0, s1;
    {
        float v = (t < NN) ? sa0[t] : -INFINITY;
        float m = block_reduce_max(v, sh);
        float e = (t < NN && t != i0) ? expf(SCALE * (v - m)) : 0.f;
        float sum = block_reduce_sum(e, sh);
        float a = e / fmaxf(sum, N_EPS);
        if (t < NN) sa0[t] = a;
        s0 = block_reduce_sum(a, sh);
    }
    {
        float v = (t < NN) ? sa1[t] : -INFINITY;
        float m = block_reduce_max(v, sh);
        float e = (t < NN && t != i0 + 1) ? expf(SCALE * (v - m)) : 0.f;
        float sum = block_reduce_sum(e, sh);
        float a = e / fmaxf(sum, N_EPS);
        if (t < NN) sa1[t] = a;
        s1 = block_reduce_sum(a, sh);
    }
    __syncthreads();
    // phase C: y = s*(P_i + bias) - sum_j a_j P_j
    const float* Pb = P + base;
    float acc0 = 0.f, acc1 = 0.f;
    #pragma unroll 8
    for (int j = 0; j < NN; j++) {
        float pv = Pb[(size_t)j * Cc + t];
        acc0 = fmaf(sa0[j], pv, acc0);
        acc1 = fmaf(sa1[j], pv, acc1);
    }
    float bv = bias[t];
    float y0 = fmaf(s0, Pb[(size_t)i0 * Cc + t] + bv, -acc0);
    float y1 = fmaf(s1, Pb[(size_t)(i0+1) * Cc + t] + bv, -acc1);
    // phase E: LayerNorm + LeakyReLU
    float gg = g[t], bbv = bb[t];
    {
        float mean = block_reduce_sum(y0, sh) * (1.f/256.f);
        float d = y0 - mean;
        float var = block_reduce_sum(d * d, sh) * (1.f/256.f);
        float z = d / sqrtf(var + LN_EPS) * gg + bbv;
        x1[base + (size_t)i0 * Cc + t] = (z >= 0.f) ? z : SLOPE * z;
    }
    {
        float mean = block_reduce_sum(y1, sh) * (1.f/256.f);
        float d = y1 - mean;
        float var = block_reduce_sum(d * d, sh) * (1.f/256.f);
        float z = d / sqrtf(var + LN_EPS) * gg + bbv;
        x1[base + (size_t)(i0+1) * Cc + t] = (z >= 0.f) ? z : SLOPE * z;
    }
}

// ---------------- dispatch 4: nf2T/M2 + lf2 ----------------
__global__ void k_mid(const float* __restrict__ x1, const float* __restrict__ fa_adj_w,
                      const float* __restrict__ WT2, const float* __restrict__ fa_aff_b,
                      float* __restrict__ nfT, float* __restrict__ M, float* __restrict__ lf2) {
    int bid = blockIdx.x;
    if (bid < RR/4) gemm4_normT(bid, x1, fa_adj_w, nfT, M);
    else            gemm4_plain(bid - RR/4, x1, WT2, fa_aff_b, lf2);
}

// ---------------- dispatch 5: feat_aggr row kernel (+ nf3 epilogue) ----------------
__global__ void k_row2(const float* __restrict__ nfT, const float* __restrict__ M,
                       const float* __restrict__ lf2, const float* __restrict__ g,
                       const float* __restrict__ bb, float* __restrict__ x2,
                       float* __restrict__ nf3) {
    __shared__ float sm0[Cc], sm1[Cc];
    __shared__ float sa0[NN], sa1[NN];
    __shared__ float sh[4];
    int t = threadIdx.x;
    int b = blockIdx.x / (NN/2);
    int i0 = (blockIdx.x % (NN/2)) * 2;
    size_t base = (size_t)b * NN * Cc;
    sm0[t] = M[base + (size_t)i0 * Cc + t];
    sm1[t] = M[base + (size_t)(i0+1) * Cc + t];
    __syncthreads();
    if (t < NN) {
        const float* nfc = nfT + (size_t)b * Cc * JP + t;
        float a0 = 0.f, a1 = 0.f;
        #pragma unroll 8
        for (int c = 0; c < Cc; c++) {
            float q = nfc[(size_t)c * JP];
            a0 = fmaf(sm0[c], q, a0);
            a1 = fmaf(sm1[c], q, a1);
        }
        sa0[t] = a0; sa1[t] = a1;
    }
    __syncthreads();
    // softmax rows
    {
        float v = (t < NN) ? sa0[t] : -INFINITY;
        float m = block_reduce_max(v, sh);
        float e = (t < NN) ? expf(SCALE * (v - m)) : 0.f;
        float sum = block_reduce_sum(e, sh);
        if (t < NN) sa0[t] = e / sum;
    }
    {
        float v = (t < NN) ? sa1[t] : -INFINITY;
        float m = block_reduce_max(v, sh);
        float e = (t < NN) ? expf(SCALE * (v - m)) : 0.f;
        float sum = block_reduce_sum(e, sh);
        if (t < NN) sa1[t] = e / sum;
    }
    __syncthreads();
    const float* l2b = lf2 + base;
    float y0 = 0.f, y1 = 0.f;
    #pragma unroll 8
    for (int j = 0; j < NN; j++) {
        float xv = l2b[(size_t)j * Cc + t];
        y0 = fmaf(sa0[j], xv, y0);
        y1 = fmaf(sa1[j], xv, y1);
    }
    float gg = g[t], bbv = bb[t];
    {
        float mean = block_reduce_sum(y0, sh) * (1.f/256.f);
        float d = y0 - mean;
        float var = block_reduce_sum(d * d, sh) * (1.f/256.f);
        float z = d / sqrtf(var + LN_EPS) * gg + bbv;
        z = (z >= 0.f) ? z : SLOPE * z;
        x2[base + (size_t)i0 * Cc + t] = z;
        float ss = block_reduce_sum(z * z, sh);
        nf3[base + (size_t)i0 * Cc + t] = z / fmaxf(sqrtf(ss), N_EPS);
    }
    {
        float mean = block_reduce_sum(y1, sh) * (1.f/256.f);
        float d = y1 - mean;
        float var = block_reduce_sum(d * d, sh) * (1.f/256.f);
        float z = d / sqrtf(var + LN_EPS) * gg + bbv;
        z = (z >= 0.f) ? z : SLOPE * z;
        x2[base + (size_t)(i0+1) * Cc + t] = z;
        float ss = block_reduce_sum(z * z, sh);
        nf3[base + (size_t)(i0+1) * Cc + t] = z / fmaxf(sqrtf(ss), N_EPS);
    }
}

// ---------------- dispatch 6: vvp[b,q,c] = sum_{j in chunk q} w[j]*nf3[b,j,c] ----------------
__global__ void k_wsum(const float* __restrict__ nf3, const float* __restrict__ w,
                       float* __restrict__ vvp) {
    int b = blockIdx.x >> 2, q = blockIdx.x & 3;
    int t = threadIdx.x;
    const float* base = nf3 + (size_t)b * NN * Cc;
    float acc = 0.f;
    int j0 = q * 50;
    #pragma unroll 10
    for (int j = j0; j < j0 + 50; j++) acc = fmaf(w[j], base[(size_t)j * Cc + t], acc);
    vvp[(size_t)(b * 4 + q) * Cc + t] = acc;
}

// ---------------- dispatch 7: out = x2 * sigmoid(nf3.vv + pos.w9 + b) ----------------
__global__ void k_natt(const float* __restrict__ x2, const float* __restrict__ nf3,
                       const float* __restrict__ vvp, const float* __restrict__ pos,
                       const float* __restrict__ w, const float* __restrict__ nb,
                       float* __restrict__ out) {
    int t = threadIdx.x, lane = t & 63, wv = t >> 6;
    int b = blockIdx.x / (NN/4);
    int i = (blockIdx.x % (NN/4)) * 4 + wv;
    size_t bi = (size_t)b * NN + i;
    const float4* vp = (const float4*)(vvp + (size_t)b * 4 * Cc);
    float4 v0 = vp[0*64 + lane], v1 = vp[1*64 + lane], v2 = vp[2*64 + lane], v3 = vp[3*64 + lane];
    float4 vb;
    vb.x = v0.x + v1.x + v2.x + v3.x;
    vb.y = v0.y + v1.y + v2.y + v3.y;
    vb.z = v0.z + v1.z + v2.z + v3.z;
    vb.w = v0.w + v1.w + v2.w + v3.w;
    float4 nv = ((const float4*)(nf3 + bi * Cc))[lane];
    float val = nv.x*vb.x + nv.y*vb.y + nv.z*vb.z + nv.w*vb.w;
    if (lane < 9) val += pos[bi * 9 + lane] * w[NN + lane];
    val = wave_reduce_sum(val);
    float att = 1.f / (1.f + expf(-(val + nb[0])));
    float4 xo = ((const float4*)(x2 + bi * Cc))[lane];
    xo.x *= att; xo.y *= att; xo.z *= att; xo.w *= att;
    ((float4*)(out + bi * Cc))[lane] = xo;
}

// ---------------- launcher ----------------
extern "C" void kernel_launch(void* const* d_in, const int* in_sizes, int n_in,
                              void* d_out, int out_size, void* d_ws, size_t ws_size,
                              hipStream_t stream) {
    (void)in_sizes; (void)n_in; (void)out_size; (void)ws_size;
    const float* lf       = (const float*)d_in[0];
    const float* pos      = (const float*)d_in[2];
    const float* dp_adj_w = (const float*)d_in[3];
    const float* dp_aff_w = (const float*)d_in[4];
    const float* dp_aff_b = (const float*)d_in[5];
    const float* dp_ln_g  = (const float*)d_in[6];
    const float* dp_ln_b  = (const float*)d_in[7];
    const float* fa_adj_w = (const float*)d_in[8];
    const float* fa_aff_w = (const float*)d_in[9];
    const float* fa_aff_b = (const float*)d_in[10];
    const float* fa_ln_g  = (const float*)d_in[11];
    const float* fa_ln_b  = (const float*)d_in[12];
    const float* na_w     = (const float*)d_in[13];
    const float* na_b     = (const float*)d_in[14];
    float* out = (float*)d_out;
    float* ws  = (float*)d_ws;

    float* nfT = ws;                   // Bn*Cc*JP = 409600 (reused stage 2)
    float* M   = nfT + Bn * Cc * JP;   // RR*Cc (reused for M2)
    float* P   = M   + RR * Cc;        // RR*Cc (reused for lf2)
    float* x1  = P   + RR * Cc;        // RR*Cc
    float* x2  = x1  + RR * Cc;        // RR*Cc
    float* nf3 = x2  + RR * Cc;        // RR*Cc
    float* WT1 = nf3 + RR * Cc;        // Cc*Cc
    float* WT2 = WT1 + Cc * Cc;        // Cc*Cc
    float* vvp = WT2 + Cc * Cc;        // Bn*4*Cc

    dim3 blk(256);
    k_pre <<<RR/4 + 128, blk, 0, stream>>>(lf, dp_adj_w, dp_aff_w, fa_aff_w, nfT, M, WT1, WT2);
    k_pre2<<<RR/4,       blk, 0, stream>>>(lf, WT1, P);
    k_row1<<<Bn * NN/2,  blk, 0, stream>>>(nfT, M, P, dp_aff_b, dp_ln_g, dp_ln_b, x1);
    k_mid <<<RR/4 * 2,   blk, 0, stream>>>(x1, fa_adj_w, WT2, fa_aff_b, nfT, M, P);
    k_row2<<<Bn * NN/2,  blk, 0, stream>>>(nfT, M, P, fa_ln_g, fa_ln_b, x2, nf3);
    k_wsum<<<Bn * 4,     blk, 0, stream>>>(nf3, na_w, vvp);
    k_natt<<<Bn * NN/4,  blk, 0, stream>>>(x2, nf3, vvp, pos, na_w, na_b, out);
}